// Round 8
// baseline (7815.138 us; speedup 1.0000x reference)
//
#include <hip/hip_runtime.h>
#include <hip/hip_bf16.h>
#include <stdint.h>

// GRU decoder: B=128, IN=256, H=512, SEQ=1024, fp32 out.
// R8: FLAGLESS tag-in-data exchange.
// 8 bg x 32 hg = 256 one-wave WGs (16 rows x 16 cols). w_hh bf16 frags in LDS.
// h exchanged as 8B system-scope relaxed atomics in A-fragment order; each ull
// carries a 4-bit version tag in the 4 bf16 mantissa LSBs: T(v)=(v%15)+1
// (poison 0xAA.. -> tag 0, never valid; b64 atomics can't tear; bg-lockstep
// bounds skew<=1 so 8 rotating buffers have no ABA). No flags, no drains, no
// fences: consumer polls the payload itself and MFMAs chunks as they arrive.

constexpr int SEQ = 1024;
constexpr int BATCH = 128;
constexpr int IND = 256;
constexpr int HD = 512;
constexpr int BG = 8;
constexpr int HG = 32;
constexpr int ROWS = BATCH / BG;   // 16
constexpr int NT = 3;              // gate tiles: r, z, n
constexpr int NBUF = 8;            // rotating h buffers

using frag16 = __attribute__((ext_vector_type(8))) short;  // 8 bf16
using f32x4  = __attribute__((ext_vector_type(4))) float;

constexpr unsigned long long TAGM = 0x0001000100010001ull;

__device__ __forceinline__ float sigmoid_f(float x) {
    return 1.f / (1.f + __expf(-x));
}
__device__ __forceinline__ float tanh_f(float x) {
    float e = __expf(2.f * x);
    return 1.f - 2.f / (e + 1.f);
}
__device__ __forceinline__ unsigned short f2bfu(float x) {
    return __bfloat16_as_ushort(__float2bfloat16(x));
}
__device__ __forceinline__ unsigned tag_of(unsigned long long a) {
    unsigned lo = (unsigned)a, hi = (unsigned)(a >> 32);
    return (lo & 1u) | ((lo >> 15) & 2u) | ((hi & 1u) << 2) | ((hi >> 13) & 8u);
}
__device__ __forceinline__ unsigned long long tag_pat(unsigned t) {
    return (unsigned long long)(t & 1u)
         | ((unsigned long long)((t >> 1) & 1u) << 16)
         | ((unsigned long long)((t >> 2) & 1u) << 32)
         | ((unsigned long long)((t >> 3) & 1u) << 48);
}

__global__ __launch_bounds__(64) void gru_kernel(
    const float* __restrict__ x,      // [128, 256]
    const float* __restrict__ w_ih,   // [1536, 256]
    const float* __restrict__ w_hh,   // [1536, 512]
    const float* __restrict__ b_ih,   // [1536]
    const float* __restrict__ b_hh,   // [1536]
    unsigned long long* __restrict__ hx,  // NBUF * BG * 2048 ull (frag-order h)
    float* __restrict__ out)              // [128, 1024, 512] fp32
{
    const int lane = threadIdx.x;
    const int bg = blockIdx.x & 7;
    const int hg = blockIdx.x >> 3;
    const int b0 = bg * ROWS;
    const int c0 = hg * 16;
    const int nlo = lane & 15;
    const int quad = lane >> 4;

    int gcol[NT];
    gcol[0] = c0 + nlo;           // r
    gcol[1] = HD + c0 + nlo;      // z
    gcol[2] = 2 * HD + c0 + nlo;  // n

    // ---- stage w_hh slice -> LDS in fragment order (once) ----
    __shared__ frag16 ldsB[NT * 16 * 64];  // 48 KB
#pragma unroll
    for (int t = 0; t < NT; ++t) {
        for (int kc = 0; kc < 16; ++kc) {
            const float* src = w_hh + (size_t)gcol[t] * HD + kc * 32 + quad * 8;
            float4 v0 = *(const float4*)src;
            float4 v1 = *(const float4*)(src + 4);
            frag16 f;
            f[0] = (short)f2bfu(v0.x); f[1] = (short)f2bfu(v0.y);
            f[2] = (short)f2bfu(v0.z); f[3] = (short)f2bfu(v0.w);
            f[4] = (short)f2bfu(v1.x); f[5] = (short)f2bfu(v1.y);
            f[6] = (short)f2bfu(v1.z); f[7] = (short)f2bfu(v1.w);
            ldsB[(t * 16 + kc) * 64 + lane] = f;
        }
    }

    // ---- gi = x @ w_ih.T + b_ih (+ b_hh folded for r,z) ----
    float gi[NT][4];
    float bhn = b_hh[gcol[2]];
#pragma unroll
    for (int t = 0; t < NT; ++t) {
        float bi = b_ih[gcol[t]] + ((t < 2) ? b_hh[gcol[t]] : 0.f);
#pragma unroll
        for (int r = 0; r < 4; ++r) gi[t][r] = bi;
    }
    for (int r = 0; r < 4; ++r) {
        const float4* xr = (const float4*)(x + (size_t)(b0 + quad * 4 + r) * IND);
        for (int kc = 0; kc < IND / 4; ++kc) {
            float4 xv = xr[kc];
#pragma unroll
            for (int t = 0; t < NT; ++t) {
                float4 wv = ((const float4*)(w_ih + (size_t)gcol[t] * IND))[kc];
                gi[t][r] += xv.x * wv.x + xv.y * wv.y + xv.z * wv.z + xv.w * wv.w;
            }
        }
    }

    // ---- recurrence ----
    float hreg[4];
#pragma unroll
    for (int r = 0; r < 4; ++r) hreg[r] = 0.f;

    for (int s = 0; s < SEQ; ++s) {
        f32x4 C[NT];
#pragma unroll
        for (int t = 0; t < NT; ++t) C[t] = (f32x4){0.f, 0.f, 0.f, 0.f};

        if (s > 0) {
            // consume version s from buffer s%NBUF, expected tag (s%15)+1
            const unsigned long long* hb =
                hx + ((size_t)(s & (NBUF - 1)) * BG + bg) * 2048 + (size_t)lane * 2;
            const unsigned expect = (unsigned)(s % 15) + 1u;
            unsigned long long a0[16], a1[16];
            unsigned valid = 0;
#pragma unroll
            for (int kc = 0; kc < 16; ++kc) {
                a0[kc] = __hip_atomic_load(hb + kc * 128,     __ATOMIC_RELAXED, __HIP_MEMORY_SCOPE_SYSTEM);
                a1[kc] = __hip_atomic_load(hb + kc * 128 + 1, __ATOMIC_RELAXED, __HIP_MEMORY_SCOPE_SYSTEM);
            }
            while (true) {
                unsigned newly = 0;
#pragma unroll
                for (int kc = 0; kc < 16; ++kc) {
                    if (!(valid & (1u << kc))) {
                        bool ok = (tag_of(a0[kc]) == expect) && (tag_of(a1[kc]) == expect);
                        if (__ballot(ok) == ~0ull) newly |= 1u << kc;
                    }
                }
#pragma unroll
                for (int kc = 0; kc < 16; ++kc) {
                    if (newly & (1u << kc)) {
                        union { unsigned long long u[2]; frag16 f; } af;
                        af.u[0] = a0[kc];
                        af.u[1] = a1[kc];
#pragma unroll
                        for (int t = 0; t < NT; ++t) {
                            frag16 bfr = ldsB[(t * 16 + kc) * 64 + lane];
                            C[t] = __builtin_amdgcn_mfma_f32_16x16x32_bf16(af.f, bfr, C[t], 0, 0, 0);
                        }
                    }
                }
                valid |= newly;
                if (valid == 0xFFFFu) break;
#pragma unroll
                for (int kc = 0; kc < 16; ++kc) {
                    if (!(valid & (1u << kc))) {
                        a0[kc] = __hip_atomic_load(hb + kc * 128,     __ATOMIC_RELAXED, __HIP_MEMORY_SCOPE_SYSTEM);
                        a1[kc] = __hip_atomic_load(hb + kc * 128 + 1, __ATOMIC_RELAXED, __HIP_MEMORY_SCOPE_SYSTEM);
                    }
                }
            }
        }

        // publish version s+1 into buffer (s+1)%NBUF with tag ((s+1)%15)+1
        unsigned long long* hw =
            hx + ((size_t)((s + 1) & (NBUF - 1)) * BG + bg) * 2048;
        const unsigned long long pat = tag_pat((unsigned)((s + 1) % 15) + 1u);
        float ov[4];
#pragma unroll
        for (int r = 0; r < 4; ++r) {
            float gr  = gi[0][r] + C[0][r];
            float gz  = gi[1][r] + C[1][r];
            float ghn = C[2][r] + bhn;
            float rr = sigmoid_f(gr);
            float zz = sigmoid_f(gz);
            float nn = tanh_f(gi[2][r] + rr * ghn);
            float hn = (1.f - zz) * nn + zz * hreg[r];
            hreg[r] = hn;
            ov[r] = hn;
            // pack 8 cols (one chunk) into lanes lane%8==0 via shfl_xor tree
            unsigned own = (unsigned)f2bfu(hn);
            unsigned v0 = own | ((unsigned)__shfl_xor((int)own, 1) << 16);
            unsigned w1 = (unsigned)__shfl_xor((int)v0, 2);
            unsigned u2 = (unsigned)__shfl_xor((int)v0, 4);
            unsigned u3 = (unsigned)__shfl_xor((int)w1, 4);
            if ((lane & 7) == 0) {
                unsigned long long lo = (unsigned long long)v0 | ((unsigned long long)w1 << 32);
                unsigned long long hi = (unsigned long long)u2 | ((unsigned long long)u3 << 32);
                lo = (lo & ~TAGM) | pat;
                hi = (hi & ~TAGM) | pat;
                size_t ci = (size_t)hg * 64 + (size_t)(nlo >> 3) * 32 + (size_t)(quad * 4 + r) * 2;
                __hip_atomic_store(hw + ci,     lo, __ATOMIC_RELAXED, __HIP_MEMORY_SCOPE_SYSTEM);
                __hip_atomic_store(hw + ci + 1, hi, __ATOMIC_RELAXED, __HIP_MEMORY_SCOPE_SYSTEM);
            }
        }

        // out stores after publish (off the critical path)
        {
            float* op = out + (size_t)(b0 + quad * 4) * (SEQ * HD) + (size_t)s * HD + c0 + nlo;
#pragma unroll
            for (int r = 0; r < 4; ++r)
                op[(size_t)r * (SEQ * HD)] = ov[r];
        }
    }
}

extern "C" void kernel_launch(void* const* d_in, const int* in_sizes, int n_in,
                              void* d_out, int out_size, void* d_ws, size_t ws_size,
                              hipStream_t stream) {
    (void)in_sizes; (void)n_in; (void)out_size; (void)ws_size;
    const float* x    = (const float*)d_in[0];
    const float* w_ih = (const float*)d_in[1];
    const float* w_hh = (const float*)d_in[2];
    const float* b_ih = (const float*)d_in[3];
    const float* b_hh = (const float*)d_in[4];

    unsigned long long* hx = (unsigned long long*)d_ws;  // 1 MB, poisoned 0xAA each launch

    gru_kernel<<<BG * HG, 64, 0, stream>>>(x, w_ih, w_hh, b_ih, b_hh, hx,
                                           (float*)d_out);
}

// Round 9
// 5397.671 us; speedup vs baseline: 1.4479x; 1.4479x over previous
//
#include <hip/hip_runtime.h>
#include <hip/hip_bf16.h>
#include <stdint.h>

// GRU decoder: B=128, IN=256, H=512, SEQ=1024, fp32 out.
// R9: SENTINEL-GATED chunk dataflow (fixes R8's poll economics).
// 8 bg x 32 hg = 256 one-wave WGs (16 rows x 16 cols). w_hh bf16 frags in LDS.
// h exchanged as 8B system-scope relaxed atomics in A-fragment order, each ull
// carrying a 4-bit version tag in the 4 bf16 mantissa LSBs (R8 scheme, proven:
// poison->tag 0 never valid; NBUF=8 + 15-tag cycle ABA-safe under lockstep
// skew<=1). NEW: consumers detect readiness via ONE sentinel ull per producer
// (32 lane-loads/retry, 64x lighter than R8's full-payload re-poll), then load
// each ready chunk once, tag-validate it, retry only stale chunks, and MFMA
// chunks as they arrive. Producer: tagged stores only - no drain/flag/fence.

constexpr int SEQ = 1024;
constexpr int BATCH = 128;
constexpr int IND = 256;
constexpr int HD = 512;
constexpr int BG = 8;
constexpr int HG = 32;
constexpr int ROWS = BATCH / BG;   // 16
constexpr int NT = 3;              // gate tiles: r, z, n
constexpr int NBUF = 8;            // rotating h buffers

using frag16 = __attribute__((ext_vector_type(8))) short;  // 8 bf16
using f32x4  = __attribute__((ext_vector_type(4))) float;

constexpr unsigned long long TAGM = 0x0001000100010001ull;

__device__ __forceinline__ float sigmoid_f(float x) {
    return 1.f / (1.f + __expf(-x));
}
__device__ __forceinline__ float tanh_f(float x) {
    float e = __expf(2.f * x);
    return 1.f - 2.f / (e + 1.f);
}
__device__ __forceinline__ unsigned short f2bfu(float x) {
    return __bfloat16_as_ushort(__float2bfloat16(x));
}
__device__ __forceinline__ unsigned tag_of(unsigned long long a) {
    unsigned lo = (unsigned)a, hi = (unsigned)(a >> 32);
    return (lo & 1u) | ((lo >> 15) & 2u) | ((hi & 1u) << 2) | ((hi >> 13) & 8u);
}
__device__ __forceinline__ unsigned long long tag_pat(unsigned t) {
    return (unsigned long long)(t & 1u)
         | ((unsigned long long)((t >> 1) & 1u) << 16)
         | ((unsigned long long)((t >> 2) & 1u) << 32)
         | ((unsigned long long)((t >> 3) & 1u) << 48);
}

__global__ __launch_bounds__(64) void gru_kernel(
    const float* __restrict__ x,      // [128, 256]
    const float* __restrict__ w_ih,   // [1536, 256]
    const float* __restrict__ w_hh,   // [1536, 512]
    const float* __restrict__ b_ih,   // [1536]
    const float* __restrict__ b_hh,   // [1536]
    unsigned long long* __restrict__ hx,  // NBUF * BG * 2048 ull (frag-order h)
    float* __restrict__ out)              // [128, 1024, 512] fp32
{
    const int lane = threadIdx.x;
    const int bg = blockIdx.x & 7;
    const int hg = blockIdx.x >> 3;
    const int b0 = bg * ROWS;
    const int c0 = hg * 16;
    const int nlo = lane & 15;
    const int quad = lane >> 4;

    int gcol[NT];
    gcol[0] = c0 + nlo;           // r
    gcol[1] = HD + c0 + nlo;      // z
    gcol[2] = 2 * HD + c0 + nlo;  // n

    // ---- stage w_hh slice -> LDS in fragment order (once) ----
    __shared__ frag16 ldsB[NT * 16 * 64];  // 48 KB
#pragma unroll
    for (int t = 0; t < NT; ++t) {
        for (int kc = 0; kc < 16; ++kc) {
            const float* src = w_hh + (size_t)gcol[t] * HD + kc * 32 + quad * 8;
            float4 v0 = *(const float4*)src;
            float4 v1 = *(const float4*)(src + 4);
            frag16 f;
            f[0] = (short)f2bfu(v0.x); f[1] = (short)f2bfu(v0.y);
            f[2] = (short)f2bfu(v0.z); f[3] = (short)f2bfu(v0.w);
            f[4] = (short)f2bfu(v1.x); f[5] = (short)f2bfu(v1.y);
            f[6] = (short)f2bfu(v1.z); f[7] = (short)f2bfu(v1.w);
            ldsB[(t * 16 + kc) * 64 + lane] = f;
        }
    }

    // ---- gi = x @ w_ih.T + b_ih (+ b_hh folded for r,z) ----
    float gi[NT][4];
    float bhn = b_hh[gcol[2]];
#pragma unroll
    for (int t = 0; t < NT; ++t) {
        float bi = b_ih[gcol[t]] + ((t < 2) ? b_hh[gcol[t]] : 0.f);
#pragma unroll
        for (int r = 0; r < 4; ++r) gi[t][r] = bi;
    }
    for (int r = 0; r < 4; ++r) {
        const float4* xr = (const float4*)(x + (size_t)(b0 + quad * 4 + r) * IND);
        for (int kc = 0; kc < IND / 4; ++kc) {
            float4 xv = xr[kc];
#pragma unroll
            for (int t = 0; t < NT; ++t) {
                float4 wv = ((const float4*)(w_ih + (size_t)gcol[t] * IND))[kc];
                gi[t][r] += xv.x * wv.x + xv.y * wv.y + xv.z * wv.z + xv.w * wv.w;
            }
        }
    }

    // ---- recurrence ----
    float hreg[4];
#pragma unroll
    for (int r = 0; r < 4; ++r) hreg[r] = 0.f;

    for (int s = 0; s < SEQ; ++s) {
        f32x4 C[NT];
#pragma unroll
        for (int t = 0; t < NT; ++t) C[t] = (f32x4){0.f, 0.f, 0.f, 0.f};

        if (s > 0) {
            // consume version s from buffer s%NBUF, expected tag (s%15)+1
            const unsigned long long* hbb =
                hx + ((size_t)(s & (NBUF - 1)) * BG + bg) * 2048;
            const unsigned long long* hb = hbb + (size_t)lane * 2;
            // sentinel: producer p's LAST-issued store is its (nlo=0,quad=0)
            // lane's r=3 second ull at p*64 + 7
            const unsigned long long* sent = hbb + (size_t)(lane & 31) * 64 + 7;
            const unsigned expect = (unsigned)(s % 15) + 1u;
            unsigned long long a0[16], a1[16];
            unsigned mask = 0;
            while (mask != 0xFFFFu) {
                // cheap readiness probe: 1 ull per producer
                unsigned long long sv = __hip_atomic_load(sent, __ATOMIC_RELAXED,
                                                          __HIP_MEMORY_SCOPE_SYSTEM);
                unsigned m32 = (unsigned)__ballot(tag_of(sv) == expect);
                unsigned pr = m32 & (m32 >> 1) & 0x55555555u;  // both producers of pair
                unsigned ready = 0;
#pragma unroll
                for (int kc = 0; kc < 16; ++kc)
                    ready |= ((pr >> (2 * kc)) & 1u) << kc;
                unsigned newly = ready & ~mask;
                if (!newly) continue;
                // batch-load the newly ready chunks
#pragma unroll
                for (int kc = 0; kc < 16; ++kc) {
                    if (newly & (1u << kc)) {
                        a0[kc] = __hip_atomic_load(hb + kc * 128,     __ATOMIC_RELAXED, __HIP_MEMORY_SCOPE_SYSTEM);
                        a1[kc] = __hip_atomic_load(hb + kc * 128 + 1, __ATOMIC_RELAXED, __HIP_MEMORY_SCOPE_SYSTEM);
                    }
                }
                // validate tags (covers sentinel optimism); keep stale for retry
                unsigned good = 0;
#pragma unroll
                for (int kc = 0; kc < 16; ++kc) {
                    if (newly & (1u << kc)) {
                        bool g = (tag_of(a0[kc]) == expect) && (tag_of(a1[kc]) == expect);
                        if (__ballot(g) == ~0ull) good |= 1u << kc;
                    }
                }
                // MFMA validated chunks as they arrive
#pragma unroll
                for (int kc = 0; kc < 16; ++kc) {
                    if (good & (1u << kc)) {
                        union { unsigned long long u[2]; frag16 f; } af;
                        af.u[0] = a0[kc];
                        af.u[1] = a1[kc];
#pragma unroll
                        for (int t = 0; t < NT; ++t) {
                            frag16 bfr = ldsB[(t * 16 + kc) * 64 + lane];
                            C[t] = __builtin_amdgcn_mfma_f32_16x16x32_bf16(af.f, bfr, C[t], 0, 0, 0);
                        }
                    }
                }
                mask |= good;
            }
        }

        // publish version s+1 into buffer (s+1)%NBUF with tag ((s+1)%15)+1
        // (stores spread across the r-loop; NO drain, NO flag, NO fence)
        unsigned long long* hw =
            hx + ((size_t)((s + 1) & (NBUF - 1)) * BG + bg) * 2048;
        const unsigned long long pat = tag_pat((unsigned)((s + 1) % 15) + 1u);
        float ov[4];
#pragma unroll
        for (int r = 0; r < 4; ++r) {
            float gr  = gi[0][r] + C[0][r];
            float gz  = gi[1][r] + C[1][r];
            float ghn = C[2][r] + bhn;
            float rr = sigmoid_f(gr);
            float zz = sigmoid_f(gz);
            float nn = tanh_f(gi[2][r] + rr * ghn);
            float hn = (1.f - zz) * nn + zz * hreg[r];
            hreg[r] = hn;
            ov[r] = hn;
            // pack 8 cols (one chunk) into lanes lane%8==0 via shfl_xor tree
            unsigned own = (unsigned)f2bfu(hn);
            unsigned v0 = own | ((unsigned)__shfl_xor((int)own, 1) << 16);
            unsigned w1 = (unsigned)__shfl_xor((int)v0, 2);
            unsigned u2 = (unsigned)__shfl_xor((int)v0, 4);
            unsigned u3 = (unsigned)__shfl_xor((int)w1, 4);
            if ((lane & 7) == 0) {
                unsigned long long lo = (unsigned long long)v0 | ((unsigned long long)w1 << 32);
                unsigned long long hi = (unsigned long long)u2 | ((unsigned long long)u3 << 32);
                lo = (lo & ~TAGM) | pat;
                hi = (hi & ~TAGM) | pat;
                size_t ci = (size_t)hg * 64 + (size_t)(nlo >> 3) * 32 + (size_t)(quad * 4 + r) * 2;
                __hip_atomic_store(hw + ci,     lo, __ATOMIC_RELAXED, __HIP_MEMORY_SCOPE_SYSTEM);
                __hip_atomic_store(hw + ci + 1, hi, __ATOMIC_RELAXED, __HIP_MEMORY_SCOPE_SYSTEM);
            }
        }

        // out stores after publish (off the critical path)
        {
            float* op = out + (size_t)(b0 + quad * 4) * (SEQ * HD) + (size_t)s * HD + c0 + nlo;
#pragma unroll
            for (int r = 0; r < 4; ++r)
                op[(size_t)r * (SEQ * HD)] = ov[r];
        }
    }
}

extern "C" void kernel_launch(void* const* d_in, const int* in_sizes, int n_in,
                              void* d_out, int out_size, void* d_ws, size_t ws_size,
                              hipStream_t stream) {
    (void)in_sizes; (void)n_in; (void)out_size; (void)ws_size;
    const float* x    = (const float*)d_in[0];
    const float* w_ih = (const float*)d_in[1];
    const float* w_hh = (const float*)d_in[2];
    const float* b_ih = (const float*)d_in[3];
    const float* b_hh = (const float*)d_in[4];

    unsigned long long* hx = (unsigned long long*)d_ws;  // 1 MB, poisoned 0xAA each launch -> tag 0 (invalid)

    gru_kernel<<<BG * HG, 64, 0, stream>>>(x, w_ih, w_hh, b_ih, b_hh, hx,
                                           (float*)d_out);
}